// Round 1
// baseline (148.315 us; speedup 1.0000x reference)
//
#include <hip/hip_runtime.h>
#include <math.h>

#define NG 8
#define NLINES 200000
#define NFACES 200000
#define PF_BASE  28800000   // float offset of faces pf region
#define BAR_BASE 32400000   // float offset of faces bar region

// cos/sin of 2*pi/8*g evaluated in f32 (matches jnp.cos/sin of f32 angles)
__constant__ float2 c_cs[8] = {
  {  1.0f,            0.0f           },
  {  0.70710678f,     0.70710678f    },
  { -4.37113883e-08f, 1.0f           },
  { -0.70710678f,     0.70710678f    },
  { -1.0f,           -8.74227766e-08f},
  { -0.70710678f,    -0.70710678f    },
  {  1.19248806e-08f,-1.0f           },
  {  0.70710678f,    -0.70710678f    },
};
__constant__ float c_fr[4] = {0.2f, 0.4f, 0.6f, 0.8f};

// ---------------- lines ----------------
// thread = (line, g) pair; 256 threads/block; 6250 blocks exactly.
__global__ __launch_bounds__(256) void lines_kernel(
    const float4* __restrict__ skel, const int2* __restrict__ lines,
    float* __restrict__ out)
{
  __shared__ float lds[256 * 18];
  const int tid = threadIdx.x;
  const int p   = blockIdx.x * 256 + tid;   // pair index in [0, 1.6e6)
  const int li  = p >> 3;
  const int g   = p & 7;

  int2 ln = lines[li];
  float4 s1 = skel[ln.x];
  float4 s2 = skel[ln.y];
  float r1 = s1.w, r2 = s2.w;

  float cx = s2.x - s1.x, cy = s2.y - s1.y, cz = s2.z - s1.z;
  float pz = (-cx - cy) / cz;
  float invp = 1.0f / sqrtf(2.0f + pz * pz);
  float d0x = invp, d0y = invp, d0z = pz * invp;
  float invc = 1.0f / sqrtf(cx * cx + cy * cy + cz * cz);
  float ax = cx * invc, ay = cy * invc, az = cz * invc;
  // kxd = cross(axis, d0)
  float kx = ay * d0z - az * d0y;
  float ky = az * d0x - ax * d0z;
  float kz = ax * d0y - ay * d0x;
  float dd = ax * d0x + ay * d0y + az * d0z;

  float2 cs = c_cs[g];
  float cA = cs.x, sA = cs.y, omc = 1.0f - cA;
  float rx = d0x * cA + kx * sA + (ax * dd) * omc;
  float ry = d0y * cA + ky * sA + (ay * dd) * omc;
  float rz = d0z * cA + kz * sA + (az * dd) * omc;
  float invr = 1.0f / sqrtf(rx * rx + ry * ry + rz * rz);
  float nx = rx * invr, ny = ry * invr, nz = rz * invr;

  float p1x = s1.x + nx * r1, p1y = s1.y + ny * r1, p1z = s1.z + nz * r1;
  float p2x = s2.x + nx * r2, p2y = s2.y + ny * r2, p2z = s2.z + nz * r2;

  float* L = &lds[tid * 18];
  L[0] = p1x; L[1] = p1y; L[2] = p1z;
  L[3] = p2x; L[4] = p2y; L[5] = p2z;
  float dx = p2x - p1x, dy = p2y - p1y, dz = p2z - p1z;
#pragma unroll
  for (int d = 0; d < 4; ++d) {
    float fr = c_fr[d];
    L[6 + 3 * d + 0] = p1x + dx * fr;
    L[6 + 3 * d + 1] = p1y + dy * fr;
    L[6 + 3 * d + 2] = p1z + dz * fr;
  }
  __syncthreads();

  // coalesced copy-out: 256*18 floats = 1152 float4 per block
  const float4* lv = (const float4*)lds;
  float4* ov = (float4*)(out + (size_t)blockIdx.x * (256 * 18));
#pragma unroll
  for (int v = tid; v < 1152; v += 256) ov[v] = lv[v];
}

// ---------------- faces ----------------
struct F3 { float x, y, z; };
__device__ __forceinline__ F3 sub3(F3 a, F3 b) { return {a.x - b.x, a.y - b.y, a.z - b.z}; }
__device__ __forceinline__ float dot3(F3 a, F3 b) { return a.x * b.x + a.y * b.y + a.z * b.z; }

__device__ __forceinline__ void cone_intersect(F3 va, float ra, F3 vb, F3 vc, F3 n,
                                               F3& ip, F3& sn)
{
  const float COS_PHI = 6.123234e-17f;
  const float c = -4.37113883e-08f;   // cos(float32(pi/2))
  const float s = 1.0f;               // sin(float32(pi/2))
  const float t = 1.0f - c;

  F3 cab = sub3(vb, va);
  F3 cac = sub3(vc, va);
  float invab = 1.0f / sqrtf(dot3(cab, cab));
  float invac = 1.0f / sqrtf(dot3(cac, cac));
  float cr = COS_PHI * ra;
  F3 pab = {va.x + cab.x * invab * cr, va.y + cab.y * invab * cr, va.z + cab.z * invab * cr};
  F3 pac = {va.x + cac.x * invac * cr, va.y + cac.y * invac * cr, va.z + cac.z * invac * cr};

  float u = cab.x, v = cab.y, w = cab.z;
  float d0 = (u * u + (v * v + w * w) * c) * n.x + (u * v * t - w * s) * n.y + (u * w * t + v * s) * n.z;
  float d1 = (u * v * t + w * s) * n.x + (v * v + (u * u + w * w) * c) * n.y + (v * w * t - u * s) * n.z;
  float d2 = (u * w * t - v * s) * n.x + (v * w * t + u * s) * n.y + (w * w + (u * u + v * v) * c) * n.z;
  F3 dir = {d0, d1, d2};

  F3 dpp = sub3(pac, pab);
  float tt = dot3(dpp, cac) / dot3(dir, cac);
  ip = {pab.x + dir.x * tt, pab.y + dir.y * tt, pab.z + dir.z * tt};
  F3 vap = sub3(ip, va);
  float snm = sqrtf(ra * ra - dot3(vap, vap));
  sn = {snm * n.x, snm * n.y, snm * n.z};
}

__global__ __launch_bounds__(256) void faces_kernel(
    const float4* __restrict__ skel, const int* __restrict__ faces,
    float* __restrict__ out)
{
  __shared__ float lds_pf[256 * 18];
  __shared__ float lds_bar[256 * 6];
  const int tid = threadIdx.x;
  const int f = blockIdx.x * 256 + tid;
  const int blk0 = blockIdx.x * 256;
  const int cnt = (NFACES - blk0) < 256 ? (NFACES - blk0) : 256;

  if (f < NFACES) {
    int i0 = faces[3 * f + 0], i1 = faces[3 * f + 1], i2 = faces[3 * f + 2];
    float4 s1 = skel[i0], s2 = skel[i1], s3 = skel[i2];
    F3 v1 = {s1.x, s1.y, s1.z}; float r1 = s1.w;
    F3 v2 = {s2.x, s2.y, s2.z}; float r2 = s2.w;
    F3 v3 = {s3.x, s3.y, s3.z}; float r3 = s3.w;

    F3 e1 = sub3(v1, v2);
    F3 e2 = sub3(v1, v3);
    F3 crx = {e1.y * e2.z - e1.z * e2.y, e1.z * e2.x - e1.x * e2.z, e1.x * e2.y - e1.y * e2.x};
    float invn = 1.0f / sqrtf(dot3(crx, crx));
    F3 nrm = {crx.x * invn, crx.y * invn, crx.z * invn};

    F3 ip1, sn1, ip2, sn2, ip3, sn3;
    cone_intersect(v1, r1, v2, v3, nrm, ip1, sn1);
    cone_intersect(v2, r2, v1, v3, nrm, ip2, sn2);
    cone_intersect(v3, r3, v1, v2, nrm, ip3, sn3);

    float* P = &lds_pf[tid * 18];
    P[0]  = ip1.x + sn1.x; P[1]  = ip1.y + sn1.y; P[2]  = ip1.z + sn1.z;
    P[3]  = ip2.x + sn2.x; P[4]  = ip2.y + sn2.y; P[5]  = ip2.z + sn2.z;
    P[6]  = ip3.x + sn3.x; P[7]  = ip3.y + sn3.y; P[8]  = ip3.z + sn3.z;
    P[9]  = ip1.x - sn1.x; P[10] = ip1.y - sn1.y; P[11] = ip1.z - sn1.z;
    P[12] = ip2.x - sn2.x; P[13] = ip2.y - sn2.y; P[14] = ip2.z - sn2.z;
    P[15] = ip3.x - sn3.x; P[16] = ip3.y - sn3.y; P[17] = ip3.z - sn3.z;

    float* B = &lds_bar[tid * 6];
    B[0] = (P[0] + P[3] + P[6]) / 3.0f;
    B[1] = (P[1] + P[4] + P[7]) / 3.0f;
    B[2] = (P[2] + P[5] + P[8]) / 3.0f;
    B[3] = (P[9]  + P[12] + P[15]) / 3.0f;
    B[4] = (P[10] + P[13] + P[16]) / 3.0f;
    B[5] = (P[11] + P[14] + P[17]) / 3.0f;
  }
  __syncthreads();

  // pf copy-out
  {
    int nfl = cnt * 18;
    float* opf = out + PF_BASE + (size_t)blk0 * 18;
    const float4* lp = (const float4*)lds_pf;
    float4* op4 = (float4*)opf;
    int nv = nfl >> 2;
    for (int v = tid; v < nv; v += 256) op4[v] = lp[v];
    for (int v = (nv << 2) + tid; v < nfl; v += 256) opf[v] = lds_pf[v];
  }
  // bar copy-out
  {
    int nfl = cnt * 6;
    float* ob = out + BAR_BASE + (size_t)blk0 * 6;
    const float4* lb = (const float4*)lds_bar;
    float4* ob4 = (float4*)ob;
    int nv = nfl >> 2;
    for (int v = tid; v < nv; v += 256) ob4[v] = lb[v];
    for (int v = (nv << 2) + tid; v < nfl; v += 256) ob[v] = lds_bar[v];
  }
}

extern "C" void kernel_launch(void* const* d_in, const int* in_sizes, int n_in,
                              void* d_out, int out_size, void* d_ws, size_t ws_size,
                              hipStream_t stream)
{
  const float4* skel  = (const float4*)d_in[0];
  const int2*   lines = (const int2*)d_in[1];
  const int*    faces = (const int*)d_in[2];
  float* out = (float*)d_out;

  // 200000 lines * 8 generators = 1,600,000 pairs = exactly 6250 blocks of 256
  lines_kernel<<<6250, 256, 0, stream>>>(skel, lines, out);
  faces_kernel<<<(NFACES + 255) / 256, 256, 0, stream>>>(skel, faces, out);
}

// Round 2
// 145.952 us; speedup vs baseline: 1.0162x; 1.0162x over previous
//
#include <hip/hip_runtime.h>
#include <math.h>

#define NG 8
#define NLINES 200000
#define NFACES 200000
#define NFACE_BLOCKS 782          // ceil(200000/256)
#define NLINE_BLOCKS 6250         // 200000*8/256 exactly
#define PF_BASE  28800000         // float offset of faces pf region
#define BAR_BASE 32400000         // float offset of faces bar region

// fast 1-ulp hardware ops
__device__ __forceinline__ float frcp(float x)  { return __builtin_amdgcn_rcpf(x); }
__device__ __forceinline__ float frsq(float x)  { return __builtin_amdgcn_rsqf(x); }
__device__ __forceinline__ float fsqrt(float x) { return __builtin_amdgcn_sqrtf(x); }

// cos/sin of 2*pi/8*g evaluated in f32 (matches jnp.cos/sin of f32 angles)
__constant__ float2 c_cs[8] = {
  {  1.0f,            0.0f           },
  {  0.70710678f,     0.70710678f    },
  { -4.37113883e-08f, 1.0f           },
  { -0.70710678f,     0.70710678f    },
  { -1.0f,           -8.74227766e-08f},
  { -0.70710678f,    -0.70710678f    },
  {  1.19248806e-08f,-1.0f           },
  {  0.70710678f,    -0.70710678f    },
};
__constant__ float c_fr[4] = {0.2f, 0.4f, 0.6f, 0.8f};

struct F3 { float x, y, z; };
__device__ __forceinline__ F3 sub3(F3 a, F3 b) { return {a.x - b.x, a.y - b.y, a.z - b.z}; }
__device__ __forceinline__ float dot3(F3 a, F3 b) { return a.x * b.x + a.y * b.y + a.z * b.z; }

__device__ __forceinline__ void cone_intersect(F3 va, float ra, F3 vb, F3 vc, F3 n,
                                               F3& ip, F3& sn)
{
  const float COS_PHI = 6.123234e-17f;
  const float c = -4.37113883e-08f;   // cos(float32(pi/2))
  const float s = 1.0f;               // sin(float32(pi/2))
  const float t = 1.0f - c;           // rounds to 1.0f

  F3 cab = sub3(vb, va);
  F3 cac = sub3(vc, va);
  float invab = frsq(dot3(cab, cab));
  float invac = frsq(dot3(cac, cac));
  float cr = COS_PHI * ra;
  F3 pab = {va.x + cab.x * invab * cr, va.y + cab.y * invab * cr, va.z + cab.z * invab * cr};
  F3 pac = {va.x + cac.x * invac * cr, va.y + cac.y * invac * cr, va.z + cac.z * invac * cr};

  float u = cab.x, v = cab.y, w = cab.z;
  float d0 = (u * u + (v * v + w * w) * c) * n.x + (u * v * t - w * s) * n.y + (u * w * t + v * s) * n.z;
  float d1 = (u * v * t + w * s) * n.x + (v * v + (u * u + w * w) * c) * n.y + (v * w * t - u * s) * n.z;
  float d2 = (u * w * t - v * s) * n.x + (v * w * t + u * s) * n.y + (w * w + (u * u + v * v) * c) * n.z;
  F3 dir = {d0, d1, d2};

  F3 dpp = sub3(pac, pab);
  float tt = dot3(dpp, cac) * frcp(dot3(dir, cac));
  ip = {pab.x + dir.x * tt, pab.y + dir.y * tt, pab.z + dir.z * tt};
  F3 vap = sub3(ip, va);
  float snm = fsqrt(ra * ra - dot3(vap, vap));
  sn = {snm * n.x, snm * n.y, snm * n.z};
}

__global__ __launch_bounds__(256) void fused_kernel(
    const float4* __restrict__ skel, const int2* __restrict__ lines,
    const int* __restrict__ faces, float* __restrict__ out)
{
  __shared__ float lds[256 * 18];   // 18432 B -> 8 blocks/CU
  const int tid = threadIdx.x;

  if (blockIdx.x >= NFACE_BLOCKS) {
    // ---------------- lines path ----------------
    const int lb = blockIdx.x - NFACE_BLOCKS;
    const int p  = lb * 256 + tid;     // pair index in [0, 1.6e6)
    const int li = p >> 3;
    const int g  = p & 7;

    int2 ln = lines[li];
    float4 s1 = skel[ln.x];
    float4 s2 = skel[ln.y];
    float r1 = s1.w, r2 = s2.w;

    float cx = s2.x - s1.x, cy = s2.y - s1.y, cz = s2.z - s1.z;
    float pz = (-cx - cy) * frcp(cz);
    float invp = frsq(2.0f + pz * pz);
    float d0x = invp, d0y = invp, d0z = pz * invp;
    float invc = frsq(cx * cx + cy * cy + cz * cz);
    float ax = cx * invc, ay = cy * invc, az = cz * invc;
    float kx = ay * d0z - az * d0y;
    float ky = az * d0x - ax * d0z;
    float kz = ax * d0y - ay * d0x;
    float dd = ax * d0x + ay * d0y + az * d0z;

    float2 cs = c_cs[g];
    float cA = cs.x, sA = cs.y, omc = 1.0f - cA;
    float rx = d0x * cA + kx * sA + (ax * dd) * omc;
    float ry = d0y * cA + ky * sA + (ay * dd) * omc;
    float rz = d0z * cA + kz * sA + (az * dd) * omc;
    float invr = frsq(rx * rx + ry * ry + rz * rz);
    float nx = rx * invr, ny = ry * invr, nz = rz * invr;

    float p1x = s1.x + nx * r1, p1y = s1.y + ny * r1, p1z = s1.z + nz * r1;
    float p2x = s2.x + nx * r2, p2y = s2.y + ny * r2, p2z = s2.z + nz * r2;

    float* L = &lds[tid * 18];
    L[0] = p1x; L[1] = p1y; L[2] = p1z;
    L[3] = p2x; L[4] = p2y; L[5] = p2z;
    float dx = p2x - p1x, dy = p2y - p1y, dz = p2z - p1z;
#pragma unroll
    for (int d = 0; d < 4; ++d) {
      float fr = c_fr[d];
      L[6 + 3 * d + 0] = p1x + dx * fr;
      L[6 + 3 * d + 1] = p1y + dy * fr;
      L[6 + 3 * d + 2] = p1z + dz * fr;
    }
    __syncthreads();

    const float4* lv = (const float4*)lds;
    float4* ov = (float4*)(out + (size_t)lb * (256 * 18));
#pragma unroll
    for (int v = tid; v < 1152; v += 256) ov[v] = lv[v];
  } else {
    // ---------------- faces path ----------------
    const int blk0 = blockIdx.x * 256;
    const int f = blk0 + tid;
    const int cnt = (NFACES - blk0) < 256 ? (NFACES - blk0) : 256;

    float b0 = 0, b1 = 0, b2 = 0, b3 = 0, b4 = 0, b5 = 0;
    if (f < NFACES) {
      int i0 = faces[3 * f + 0], i1 = faces[3 * f + 1], i2 = faces[3 * f + 2];
      float4 s1 = skel[i0], s2 = skel[i1], s3 = skel[i2];
      F3 v1 = {s1.x, s1.y, s1.z}; float r1 = s1.w;
      F3 v2 = {s2.x, s2.y, s2.z}; float r2 = s2.w;
      F3 v3 = {s3.x, s3.y, s3.z}; float r3 = s3.w;

      F3 e1 = sub3(v1, v2);
      F3 e2 = sub3(v1, v3);
      F3 crx = {e1.y * e2.z - e1.z * e2.y, e1.z * e2.x - e1.x * e2.z, e1.x * e2.y - e1.y * e2.x};
      float invn = frsq(dot3(crx, crx));
      F3 nrm = {crx.x * invn, crx.y * invn, crx.z * invn};

      F3 ip1, sn1, ip2, sn2, ip3, sn3;
      cone_intersect(v1, r1, v2, v3, nrm, ip1, sn1);
      cone_intersect(v2, r2, v1, v3, nrm, ip2, sn2);
      cone_intersect(v3, r3, v1, v2, nrm, ip3, sn3);

      float* P = &lds[tid * 18];
      float q0  = ip1.x + sn1.x, q1  = ip1.y + sn1.y, q2  = ip1.z + sn1.z;
      float q3  = ip2.x + sn2.x, q4  = ip2.y + sn2.y, q5  = ip2.z + sn2.z;
      float q6  = ip3.x + sn3.x, q7  = ip3.y + sn3.y, q8  = ip3.z + sn3.z;
      float q9  = ip1.x - sn1.x, q10 = ip1.y - sn1.y, q11 = ip1.z - sn1.z;
      float q12 = ip2.x - sn2.x, q13 = ip2.y - sn2.y, q14 = ip2.z - sn2.z;
      float q15 = ip3.x - sn3.x, q16 = ip3.y - sn3.y, q17 = ip3.z - sn3.z;
      P[0]=q0; P[1]=q1; P[2]=q2; P[3]=q3; P[4]=q4; P[5]=q5;
      P[6]=q6; P[7]=q7; P[8]=q8; P[9]=q9; P[10]=q10; P[11]=q11;
      P[12]=q12; P[13]=q13; P[14]=q14; P[15]=q15; P[16]=q16; P[17]=q17;

      const float third = 0.33333334f;
      b0 = (q0 + q3 + q6) * third;
      b1 = (q1 + q4 + q7) * third;
      b2 = (q2 + q5 + q8) * third;
      b3 = (q9 + q12 + q15) * third;
      b4 = (q10 + q13 + q16) * third;
      b5 = (q11 + q14 + q17) * third;
    }
    __syncthreads();

    // pf copy-out (cnt*18 always divisible by 4 here: cnt is 256 or 64)
    {
      int nfl = cnt * 18;
      float* opf = out + PF_BASE + (size_t)blk0 * 18;
      const float4* lp = (const float4*)lds;
      float4* op4 = (float4*)opf;
      int nv = nfl >> 2;
      for (int v = tid; v < nv; v += 256) op4[v] = lp[v];
      for (int v = (nv << 2) + tid; v < nfl; v += 256) opf[v] = lds[v];
    }
    __syncthreads();   // all pf reads done before reuse

    if (f < NFACES) {
      float* B = &lds[tid * 6];
      B[0] = b0; B[1] = b1; B[2] = b2; B[3] = b3; B[4] = b4; B[5] = b5;
    }
    __syncthreads();

    // bar copy-out
    {
      int nfl = cnt * 6;
      float* ob = out + BAR_BASE + (size_t)blk0 * 6;
      const float4* lb4 = (const float4*)lds;
      float4* ob4 = (float4*)ob;
      int nv = nfl >> 2;
      for (int v = tid; v < nv; v += 256) ob4[v] = lb4[v];
      for (int v = (nv << 2) + tid; v < nfl; v += 256) ob[v] = lds[v];
    }
  }
}

extern "C" void kernel_launch(void* const* d_in, const int* in_sizes, int n_in,
                              void* d_out, int out_size, void* d_ws, size_t ws_size,
                              hipStream_t stream)
{
  const float4* skel  = (const float4*)d_in[0];
  const int2*   lines = (const int2*)d_in[1];
  const int*    faces = (const int*)d_in[2];
  float* out = (float*)d_out;

  fused_kernel<<<NFACE_BLOCKS + NLINE_BLOCKS, 256, 0, stream>>>(skel, lines, faces, out);
}